// Round 1
// baseline (1044.751 us; speedup 1.0000x reference)
//
#include <hip/hip_runtime.h>
#include <cstdint>
#include <cstddef>

// GCN: h1 = relu(Â (x W1) + b1); h2 = relu(Â (h1 W2) + b2);
// g = mean-pool(h2 by batch); out = log_softmax(relu(g Wl1 + bl1) Wl2 + bl2)
// Â = D^-1/2 (A + I) D^-1/2 with in-degree (by col) including self-loops.

#define HF 64  // feature width for both layers

// ---- degree / normalization ------------------------------------------------
__global__ __launch_bounds__(256) void k_init_deg(float* __restrict__ deg, int N) {
    int i = blockIdx.x * 256 + threadIdx.x;
    if (i < N) deg[i] = 1.0f;  // self-loop
}

__global__ __launch_bounds__(256) void k_count_deg(const int* __restrict__ cols,
                                                   float* __restrict__ deg, int E) {
    int i = blockIdx.x * 256 + threadIdx.x;
    if (i < E) atomicAdd(&deg[cols[i]], 1.0f);
}

__global__ __launch_bounds__(256) void k_dis(float* __restrict__ deg, int N) {
    int i = blockIdx.x * 256 + threadIdx.x;
    if (i < N) deg[i] = rsqrtf(deg[i]);  // deg >= 1 always (self-loop)
}

// ---- dense transform: OUT[N,64] = act(X[N,64]) @ W[64,64] ------------------
// Block: 256 threads, 64 rows per block. Thread = (rg=tid>>4 -> 4 rows, cg=tid&15 -> 4 cols).
// W staged in LDS (b128 reads), X staged in LDS (stride 68 to keep float4 stores aligned,
// broadcast b32 reads).
template <int RELU_IN>
__global__ __launch_bounds__(256) void k_gemm64(const float* __restrict__ X,
                                                const float* __restrict__ W,
                                                float* __restrict__ OUT, int N) {
    __shared__ float ws[64 * 64];
    __shared__ float xs[64 * 68];
    const int tid  = threadIdx.x;
    const int row0 = blockIdx.x * 64;

#pragma unroll
    for (int i = 0; i < 4; ++i) {
        int idx4 = i * 256 + tid;  // [0,1024) float4s of W
        *(float4*)&ws[idx4 * 4] = ((const float4*)W)[idx4];
    }
#pragma unroll
    for (int i = 0; i < 4; ++i) {
        int idx4 = i * 256 + tid;        // [0,1024) float4s of X tile
        int r    = idx4 >> 4;            // tile row [0,64)
        int kk   = (idx4 & 15) << 2;     // k start
        float4 v = float4{0.f, 0.f, 0.f, 0.f};
        int row  = row0 + r;
        if (row < N) v = ((const float4*)(X + (size_t)row * HF))[idx4 & 15];
        if (RELU_IN) {
            v.x = fmaxf(v.x, 0.f); v.y = fmaxf(v.y, 0.f);
            v.z = fmaxf(v.z, 0.f); v.w = fmaxf(v.w, 0.f);
        }
        *(float4*)&xs[r * 68 + kk] = v;  // 68*4 bytes row stride: 16B-aligned
    }
    __syncthreads();

    const int rg = tid >> 4;   // row group [0,16): rows rg*4..+3
    const int cg = tid & 15;   // col group: cols cg*4..+3
    float4 a0 = float4{0.f, 0.f, 0.f, 0.f};
    float4 a1 = a0, a2 = a0, a3 = a0;

#pragma unroll
    for (int k = 0; k < 64; ++k) {
        float4 wv = *(float4*)&ws[k * 64 + cg * 4];
        float  x0 = xs[(rg * 4 + 0) * 68 + k];
        float  x1 = xs[(rg * 4 + 1) * 68 + k];
        float  x2 = xs[(rg * 4 + 2) * 68 + k];
        float  x3 = xs[(rg * 4 + 3) * 68 + k];
        a0.x += x0 * wv.x; a0.y += x0 * wv.y; a0.z += x0 * wv.z; a0.w += x0 * wv.w;
        a1.x += x1 * wv.x; a1.y += x1 * wv.y; a1.z += x1 * wv.z; a1.w += x1 * wv.w;
        a2.x += x2 * wv.x; a2.y += x2 * wv.y; a2.z += x2 * wv.z; a2.w += x2 * wv.w;
        a3.x += x3 * wv.x; a3.y += x3 * wv.y; a3.z += x3 * wv.z; a3.w += x3 * wv.w;
    }

    float4 accs[4] = {a0, a1, a2, a3};
#pragma unroll
    for (int j = 0; j < 4; ++j) {
        int row = row0 + rg * 4 + j;
        if (row < N) *(float4*)&OUT[(size_t)row * HF + cg * 4] = accs[j];
    }
}

// ---- self-loop + bias init: agg[n][f] = dis[n]^2 * h[n][f] + b[f] ----------
__global__ __launch_bounds__(256) void k_init_agg(const float* __restrict__ dis,
                                                  const float* __restrict__ h,
                                                  const float* __restrict__ b,
                                                  float* __restrict__ agg, int N) {
    int idx4 = blockIdx.x * 256 + threadIdx.x;  // float4 index
    if (idx4 >= N * 16) return;
    int n  = idx4 >> 4;
    int f4 = (idx4 & 15) << 2;
    float d  = dis[n];
    float s  = d * d;
    float4 hv = ((const float4*)h)[idx4];
    float4 bv = *(const float4*)&b[f4];
    float4 o;
    o.x = s * hv.x + bv.x; o.y = s * hv.y + bv.y;
    o.z = s * hv.z + bv.z; o.w = s * hv.w + bv.w;
    ((float4*)agg)[idx4] = o;
}

// ---- edge scatter: agg[col] += dis[row]*dis[col] * h[row] ------------------
// One wave per edge iteration; lane = feature. Coalesced 256B gather + 256B atomic.
__global__ __launch_bounds__(256) void k_scatter(const int* __restrict__ rows,
                                                 const int* __restrict__ cols,
                                                 const float* __restrict__ dis,
                                                 const float* __restrict__ h,
                                                 float* __restrict__ agg, int E) {
    const int lane = threadIdx.x & 63;
    const int wid  = blockIdx.x * 4 + (threadIdx.x >> 6);
    const int nw   = gridDim.x * 4;
    for (int e = wid; e < E; e += nw) {
        int r = rows[e];
        int c = cols[e];
        float nrm = dis[r] * dis[c];
        float v   = nrm * h[(size_t)r * HF + lane];
        atomicAdd(&agg[(size_t)c * HF + lane], v);
    }
}

// ---- pooling ---------------------------------------------------------------
__global__ __launch_bounds__(256) void k_zero(float* __restrict__ p, int n) {
    int i = blockIdx.x * 256 + threadIdx.x;
    if (i < n) p[i] = 0.f;
}

// batch_index is sorted: run-length accumulate per wave, one atomic per (run, feature).
__global__ __launch_bounds__(256) void k_pool(const float* __restrict__ agg,
                                              const int* __restrict__ batch,
                                              float* __restrict__ sums,
                                              float* __restrict__ cnt, int N) {
    const int NODES_PER_WAVE = 256;
    const int lane = threadIdx.x & 63;
    const int wid  = blockIdx.x * 4 + (threadIdx.x >> 6);
    int start = wid * NODES_PER_WAVE;
    if (start >= N) return;
    int end = min(start + NODES_PER_WAVE, N);
    int cur = batch[start];
    float acc = 0.f, cc = 0.f;
    for (int n = start; n < end; ++n) {
        int b = batch[n];  // wave-uniform
        if (b != cur) {
            atomicAdd(&sums[cur * HF + lane], acc);
            if (lane == 0) atomicAdd(&cnt[cur], cc);
            acc = 0.f; cc = 0.f; cur = b;
        }
        acc += fmaxf(agg[(size_t)n * HF + lane], 0.f);  // relu fused
        cc  += 1.f;
    }
    atomicAdd(&sums[cur * HF + lane], acc);
    if (lane == 0) atomicAdd(&cnt[cur], cc);
}

// ---- MLP head --------------------------------------------------------------
// hid[g][j] = relu(bl1[j] + sum_k (sums[g][k]/cnt[g]) * Wl1[k][j]); 256 graphs x 32 hidden.
__global__ __launch_bounds__(256) void k_head1(const float* __restrict__ sums,
                                               const float* __restrict__ cnt,
                                               const float* __restrict__ Wl1,
                                               const float* __restrict__ bl1,
                                               float* __restrict__ hid) {
    int tid = threadIdx.x;
    int g   = blockIdx.x * 8 + (tid >> 5);
    int j   = tid & 31;
    float rinv = 1.0f / fmaxf(cnt[g], 1.0f);
    float a = bl1[j];
#pragma unroll
    for (int k = 0; k < 64; ++k)
        a += (sums[g * HF + k] * rinv) * Wl1[k * 32 + j];
    hid[g * 32 + j] = fmaxf(a, 0.f);
}

__global__ __launch_bounds__(256) void k_head2(const float* __restrict__ hid,
                                               const float* __restrict__ Wl2,
                                               const float* __restrict__ bl2,
                                               float* __restrict__ out) {
    int g = threadIdx.x;  // 256 graphs
    float l0 = bl2[0], l1 = bl2[1];
#pragma unroll
    for (int j = 0; j < 32; ++j) {
        float hv = hid[g * 32 + j];
        l0 += hv * Wl2[2 * j];
        l1 += hv * Wl2[2 * j + 1];
    }
    float m   = fmaxf(l0, l1);
    float lse = m + logf(expf(l0 - m) + expf(l1 - m));
    out[2 * g]     = l0 - lse;
    out[2 * g + 1] = l1 - lse;
}

// ---- driver ----------------------------------------------------------------
extern "C" void kernel_launch(void* const* d_in, const int* in_sizes, int n_in,
                              void* d_out, int out_size, void* d_ws, size_t ws_size,
                              hipStream_t stream) {
    const float* x   = (const float*)d_in[0];
    const int*   ei  = (const int*)d_in[1];
    const int*   bi  = (const int*)d_in[2];
    const float* W1  = (const float*)d_in[3];
    const float* b1  = (const float*)d_in[4];
    const float* W2  = (const float*)d_in[5];
    const float* b2  = (const float*)d_in[6];
    const float* Wl1 = (const float*)d_in[7];
    const float* bl1 = (const float*)d_in[8];
    const float* Wl2 = (const float*)d_in[9];
    const float* bl2 = (const float*)d_in[10];
    float* out = (float*)d_out;

    const int N = in_sizes[0] / HF;
    const int E = in_sizes[1] / 2;
    const int* rows = ei;       // edge_index[0] = sources
    const int* cols = ei + E;   // edge_index[1] = targets

    // workspace layout (floats): dis | h | agg | sums | cnt | hid  (~51.7 MB)
    float* ws = (float*)d_ws;
    size_t o = 0;
    float* dis  = ws + o; o += ((size_t)N + 63) / 64 * 64;
    float* h    = ws + o; o += (size_t)N * HF;
    float* agg  = ws + o; o += (size_t)N * HF;
    float* sums = ws + o; o += 256 * HF;
    float* cnt  = ws + o; o += 256;          // contiguous after sums (zeroed together)
    float* hid  = ws + o; o += 256 * 32;

    const int nb = (N + 255) / 256;
    const int eb = (E + 255) / 256;
    const int gb = (N + 63) / 64;
    const int ab = (N * 16 + 255) / 256;

    // normalization
    k_init_deg<<<nb, 256, 0, stream>>>(dis, N);
    k_count_deg<<<eb, 256, 0, stream>>>(cols, dis, E);
    k_dis<<<nb, 256, 0, stream>>>(dis, N);

    // layer 1: h = x@W1; agg = dis^2*h + b1; agg += scatter
    k_gemm64<0><<<gb, 256, 0, stream>>>(x, W1, h, N);
    k_init_agg<<<ab, 256, 0, stream>>>(dis, h, b1, agg, N);
    k_scatter<<<2048, 256, 0, stream>>>(rows, cols, dis, h, agg, E);

    // layer 2: h = relu(agg)@W2; agg = dis^2*h + b2; agg += scatter
    k_gemm64<1><<<gb, 256, 0, stream>>>(agg, W2, h, N);
    k_init_agg<<<ab, 256, 0, stream>>>(dis, h, b2, agg, N);
    k_scatter<<<2048, 256, 0, stream>>>(rows, cols, dis, h, agg, E);

    // mean pool (relu fused) + head
    k_zero<<<(256 * HF + 256 + 255) / 256, 256, 0, stream>>>(sums, 256 * HF + 256);
    {
        int pw = (N + 255) / 256;          // waves (256 nodes each)
        int pb = (pw + 3) / 4;             // 4 waves per block
        k_pool<<<pb, 256, 0, stream>>>(agg, bi, sums, cnt, N);
    }
    k_head1<<<32, 256, 0, stream>>>(sums, cnt, Wl1, bl1, hid);
    k_head2<<<1, 256, 0, stream>>>(hid, Wl2, bl2, out);
}

// Round 2
// 679.699 us; speedup vs baseline: 1.5371x; 1.5371x over previous
//
#include <hip/hip_runtime.h>
#include <cstdint>
#include <cstddef>

// GCN: h1 = relu(Â (x W1) + b1); h2 = relu(Â (h1 W2) + b2);
// g = mean-pool(h2 by batch); out = log_softmax(relu(g Wl1 + bl1) Wl2 + bl2)
// Â = D^-1/2 (A + I) D^-1/2 with in-degree (by col) including self-loops.
//
// R2: scatter-atomic aggregation (400MB HBM writes/layer, atomic-RMW bound)
// replaced by CSR gather: counting-sort edges by destination once, then one
// wave per node accumulates in registers and writes agg exactly once.

#define HF 64          // feature width for both layers
#define SCAN_CHUNK 2048

// ---- generic zero ----------------------------------------------------------
__global__ __launch_bounds__(256) void k_zero(unsigned* __restrict__ p, int n) {
    int i = blockIdx.x * 256 + threadIdx.x;
    if (i < n) p[i] = 0u;
}

// ---- degree histogram (by destination col) ---------------------------------
__global__ __launch_bounds__(256) void k_hist(const int* __restrict__ cols,
                                              unsigned* __restrict__ counts, int E) {
    int i = blockIdx.x * 256 + threadIdx.x;
    if (i < E) atomicAdd(&counts[cols[i]], 1u);
}

// ---- dis = rsqrt(deg), deg includes self-loop ------------------------------
__global__ __launch_bounds__(256) void k_dis(const unsigned* __restrict__ counts,
                                             float* __restrict__ dis, int N) {
    int i = blockIdx.x * 256 + threadIdx.x;
    if (i < N) dis[i] = rsqrtf(1.0f + (float)counts[i]);
}

// ---- exclusive scan (3 kernels): in-place over counts -> start offsets -----
__global__ __launch_bounds__(256) void k_scan1(unsigned* __restrict__ data,
                                               unsigned* __restrict__ blocksums, int n) {
    __shared__ unsigned lds[256];
    const int tid  = threadIdx.x;
    const int base = blockIdx.x * SCAN_CHUNK;
    const int i0   = base + tid * 8;
    unsigned v[8];
    unsigned s = 0;
#pragma unroll
    for (int j = 0; j < 8; ++j) {
        int i = i0 + j;
        v[j] = (i < n) ? data[i] : 0u;
        s += v[j];
    }
    lds[tid] = s;
    __syncthreads();
    // Hillis-Steele inclusive scan over 256 thread sums
    for (int off = 1; off < 256; off <<= 1) {
        unsigned t = (tid >= off) ? lds[tid - off] : 0u;
        __syncthreads();
        lds[tid] += t;
        __syncthreads();
    }
    unsigned run = (tid > 0) ? lds[tid - 1] : 0u;  // exclusive base
    if (tid == 255) blocksums[blockIdx.x] = lds[255];
#pragma unroll
    for (int j = 0; j < 8; ++j) {
        int i = i0 + j;
        if (i < n) data[i] = run;
        run += v[j];
    }
}

__global__ void k_scan2(unsigned* __restrict__ blocksums, int nb) {
    if (blockIdx.x == 0 && threadIdx.x == 0) {
        unsigned run = 0;
        for (int b = 0; b < nb; ++b) { unsigned t = blocksums[b]; blocksums[b] = run; run += t; }
    }
}

__global__ __launch_bounds__(256) void k_scan3(unsigned* __restrict__ data,
                                               const unsigned* __restrict__ blocksums, int n) {
    int i = blockIdx.x * 256 + threadIdx.x;
    if (i < n) data[i] += blocksums[i / SCAN_CHUNK];
}

// ---- CSR placement: cursor is rowptr itself (becomes shifted-by-one) -------
// After this kernel rowptr[c] == original rowptr[c+1]; node n's edges are
// [ n? rowptr[n-1] : 0 , rowptr[n] ).
__global__ __launch_bounds__(256) void k_place(const int* __restrict__ rows,
                                               const int* __restrict__ cols,
                                               unsigned* __restrict__ cursor,
                                               int* __restrict__ eidx, int E) {
    int e = blockIdx.x * 256 + threadIdx.x;
    if (e < E) {
        int c = cols[e];
        unsigned pos = atomicAdd(&cursor[c], 1u);
        eidx[pos] = rows[e];
    }
}

// ---- dense transform: OUT[N,64] = act(X[N,64]) @ W[64,64] ------------------
template <int RELU_IN>
__global__ __launch_bounds__(256) void k_gemm64(const float* __restrict__ X,
                                                const float* __restrict__ W,
                                                float* __restrict__ OUT, int N) {
    __shared__ float ws[64 * 64];
    __shared__ float xs[64 * 68];
    const int tid  = threadIdx.x;
    const int row0 = blockIdx.x * 64;

#pragma unroll
    for (int i = 0; i < 4; ++i) {
        int idx4 = i * 256 + tid;
        *(float4*)&ws[idx4 * 4] = ((const float4*)W)[idx4];
    }
#pragma unroll
    for (int i = 0; i < 4; ++i) {
        int idx4 = i * 256 + tid;
        int r    = idx4 >> 4;
        int kk   = (idx4 & 15) << 2;
        float4 v = float4{0.f, 0.f, 0.f, 0.f};
        int row  = row0 + r;
        if (row < N) v = ((const float4*)(X + (size_t)row * HF))[idx4 & 15];
        if (RELU_IN) {
            v.x = fmaxf(v.x, 0.f); v.y = fmaxf(v.y, 0.f);
            v.z = fmaxf(v.z, 0.f); v.w = fmaxf(v.w, 0.f);
        }
        *(float4*)&xs[r * 68 + kk] = v;
    }
    __syncthreads();

    const int rg = tid >> 4;
    const int cg = tid & 15;
    float4 a0 = float4{0.f, 0.f, 0.f, 0.f};
    float4 a1 = a0, a2 = a0, a3 = a0;

#pragma unroll
    for (int k = 0; k < 64; ++k) {
        float4 wv = *(float4*)&ws[k * 64 + cg * 4];
        float  x0 = xs[(rg * 4 + 0) * 68 + k];
        float  x1 = xs[(rg * 4 + 1) * 68 + k];
        float  x2 = xs[(rg * 4 + 2) * 68 + k];
        float  x3 = xs[(rg * 4 + 3) * 68 + k];
        a0.x += x0 * wv.x; a0.y += x0 * wv.y; a0.z += x0 * wv.z; a0.w += x0 * wv.w;
        a1.x += x1 * wv.x; a1.y += x1 * wv.y; a1.z += x1 * wv.z; a1.w += x1 * wv.w;
        a2.x += x2 * wv.x; a2.y += x2 * wv.y; a2.z += x2 * wv.z; a2.w += x2 * wv.w;
        a3.x += x3 * wv.x; a3.y += x3 * wv.y; a3.z += x3 * wv.z; a3.w += x3 * wv.w;
    }

    float4 accs[4] = {a0, a1, a2, a3};
#pragma unroll
    for (int j = 0; j < 4; ++j) {
        int row = row0 + rg * 4 + j;
        if (row < N) *(float4*)&OUT[(size_t)row * HF + cg * 4] = accs[j];
    }
}

// ---- CSR gather aggregation ------------------------------------------------
// agg[n] = dis[n] * ( sum_{r in nbrs(n)} dis[r]*h[r] + dis[n]*h[n] ) + b
// One wave per node, lane = feature (256B coalesced gathers, single write).
__global__ __launch_bounds__(256) void k_gather(const unsigned* __restrict__ rowptr,
                                                const int* __restrict__ eidx,
                                                const float* __restrict__ dis,
                                                const float* __restrict__ h,
                                                const float* __restrict__ b,
                                                float* __restrict__ agg, int N) {
    const int lane = threadIdx.x & 63;
    const int n    = blockIdx.x * 4 + (threadIdx.x >> 6);
    if (n >= N) return;
    unsigned end   = rowptr[n];
    unsigned start = (n > 0) ? rowptr[n - 1] : 0u;
    float dn  = dis[n];
    float acc = 0.f;
    unsigned e = start;
    for (; e + 2 <= end; e += 2) {
        int r0 = eidx[e], r1 = eidx[e + 1];
        float d0 = dis[r0], d1 = dis[r1];
        float h0 = h[(size_t)r0 * HF + lane];
        float h1 = h[(size_t)r1 * HF + lane];
        acc += d0 * h0 + d1 * h1;
    }
    if (e < end) {
        int r = eidx[e];
        acc += dis[r] * h[(size_t)r * HF + lane];
    }
    acc += dn * h[(size_t)n * HF + lane];  // self-loop
    agg[(size_t)n * HF + lane] = dn * acc + b[lane];
}

// ---- pooling (batch_index sorted: run-length, few atomics) -----------------
__global__ __launch_bounds__(256) void k_pool(const float* __restrict__ agg,
                                              const int* __restrict__ batch,
                                              float* __restrict__ sums,
                                              float* __restrict__ cnt, int N) {
    const int NODES_PER_WAVE = 256;
    const int lane = threadIdx.x & 63;
    const int wid  = blockIdx.x * 4 + (threadIdx.x >> 6);
    int start = wid * NODES_PER_WAVE;
    if (start >= N) return;
    int end = min(start + NODES_PER_WAVE, N);
    int cur = batch[start];
    float acc = 0.f, cc = 0.f;
    for (int n = start; n < end; ++n) {
        int b = batch[n];
        if (b != cur) {
            atomicAdd(&sums[cur * HF + lane], acc);
            if (lane == 0) atomicAdd(&cnt[cur], cc);
            acc = 0.f; cc = 0.f; cur = b;
        }
        acc += fmaxf(agg[(size_t)n * HF + lane], 0.f);  // relu fused
        cc  += 1.f;
    }
    atomicAdd(&sums[cur * HF + lane], acc);
    if (lane == 0) atomicAdd(&cnt[cur], cc);
}

// ---- MLP head --------------------------------------------------------------
__global__ __launch_bounds__(256) void k_head1(const float* __restrict__ sums,
                                               const float* __restrict__ cnt,
                                               const float* __restrict__ Wl1,
                                               const float* __restrict__ bl1,
                                               float* __restrict__ hid) {
    int tid = threadIdx.x;
    int g   = blockIdx.x * 8 + (tid >> 5);
    int j   = tid & 31;
    float rinv = 1.0f / fmaxf(cnt[g], 1.0f);
    float a = bl1[j];
#pragma unroll
    for (int k = 0; k < 64; ++k)
        a += (sums[g * HF + k] * rinv) * Wl1[k * 32 + j];
    hid[g * 32 + j] = fmaxf(a, 0.f);
}

__global__ __launch_bounds__(256) void k_head2(const float* __restrict__ hid,
                                               const float* __restrict__ Wl2,
                                               const float* __restrict__ bl2,
                                               float* __restrict__ out) {
    int g = threadIdx.x;
    float l0 = bl2[0], l1 = bl2[1];
#pragma unroll
    for (int j = 0; j < 32; ++j) {
        float hv = hid[g * 32 + j];
        l0 += hv * Wl2[2 * j];
        l1 += hv * Wl2[2 * j + 1];
    }
    float m   = fmaxf(l0, l1);
    float lse = m + logf(expf(l0 - m) + expf(l1 - m));
    out[2 * g]     = l0 - lse;
    out[2 * g + 1] = l1 - lse;
}

// ---- driver ----------------------------------------------------------------
extern "C" void kernel_launch(void* const* d_in, const int* in_sizes, int n_in,
                              void* d_out, int out_size, void* d_ws, size_t ws_size,
                              hipStream_t stream) {
    const float* x   = (const float*)d_in[0];
    const int*   ei  = (const int*)d_in[1];
    const int*   bi  = (const int*)d_in[2];
    const float* W1  = (const float*)d_in[3];
    const float* b1  = (const float*)d_in[4];
    const float* W2  = (const float*)d_in[5];
    const float* b2  = (const float*)d_in[6];
    const float* Wl1 = (const float*)d_in[7];
    const float* bl1 = (const float*)d_in[8];
    const float* Wl2 = (const float*)d_in[9];
    const float* bl2 = (const float*)d_in[10];
    float* out = (float*)d_out;

    const int N = in_sizes[0] / HF;
    const int E = in_sizes[1] / 2;
    const int* rows = ei;       // edge_index[0] = sources
    const int* cols = ei + E;   // edge_index[1] = targets

    // workspace layout (4B units): dis | h | agg | rowptr | blocksums | eidx |
    //                              sums | cnt | hid   (~58.5 MB)
    float* ws = (float*)d_ws;
    size_t o = 0;
    float*    dis    = ws + o; o += ((size_t)N + 63) / 64 * 64;
    float*    h      = ws + o; o += (size_t)N * HF;
    float*    agg    = ws + o; o += (size_t)N * HF;
    unsigned* rowptr = (unsigned*)(ws + o); o += ((size_t)N + 63) / 64 * 64;
    unsigned* bsums  = (unsigned*)(ws + o); o += 1024;
    int*      eidx   = (int*)(ws + o); o += (size_t)E;
    float*    sums   = ws + o; o += 256 * HF;
    float*    cnt    = ws + o; o += 256;
    float*    hid    = ws + o; o += 256 * 32;

    const int nb = (N + 255) / 256;
    const int eb = (E + 255) / 256;
    const int gb = (N + 63) / 64;
    const int sb = (N + SCAN_CHUNK - 1) / SCAN_CHUNK;  // scan blocks

    // CSR build (shared by both layers) + normalization
    k_zero<<<nb, 256, 0, stream>>>(rowptr, N);
    k_hist<<<eb, 256, 0, stream>>>(cols, rowptr, E);
    k_dis<<<nb, 256, 0, stream>>>(rowptr, dis, N);
    k_scan1<<<sb, 256, 0, stream>>>(rowptr, bsums, N);
    k_scan2<<<1, 64, 0, stream>>>(bsums, sb);
    k_scan3<<<nb, 256, 0, stream>>>(rowptr, bsums, N);
    k_place<<<eb, 256, 0, stream>>>(rows, cols, rowptr, eidx, E);

    // layer 1
    k_gemm64<0><<<gb, 256, 0, stream>>>(x, W1, h, N);
    k_gather<<<(N + 3) / 4, 256, 0, stream>>>(rowptr, eidx, dis, h, b1, agg, N);

    // layer 2
    k_gemm64<1><<<gb, 256, 0, stream>>>(agg, W2, h, N);
    k_gather<<<(N + 3) / 4, 256, 0, stream>>>(rowptr, eidx, dis, h, b2, agg, N);

    // mean pool (relu fused) + head
    k_zero<<<(256 * HF + 256 + 255) / 256, 256, 0, stream>>>((unsigned*)sums, 256 * HF + 256);
    {
        int pw = (N + 255) / 256;
        int pb = (pw + 3) / 4;
        k_pool<<<pb, 256, 0, stream>>>(agg, bi, sums, cnt, N);
    }
    k_head1<<<32, 256, 0, stream>>>(sums, cnt, Wl1, bl1, hid);
    k_head2<<<1, 256, 0, stream>>>(hid, Wl2, bl2, out);
}

// Round 3
// 514.561 us; speedup vs baseline: 2.0304x; 1.3209x over previous
//
#include <hip/hip_runtime.h>
#include <cstdint>
#include <cstddef>

// GCN: h1 = relu(Â (x W1) + b1); h2 = relu(Â (h1 W2) + b2);
// g = mean-pool(h2 by batch); out = log_softmax(relu(g Wl1 + bl1) Wl2 + bl2)
// Â = D^-1/2 (A + I) D^-1/2 with in-degree (by col) including self-loops.
//
// R3: single-level counting sort wrote 106MB to HBM (4B random scatters ->
// partial-line evictions). Replaced with two-level bucket sort: coarse
// partition with LDS reordering (coalesced run writes), then per-bucket
// node-level placement entirely in LDS (output segment streamed coalesced).
// Node degree/scan/dis all computed inside the per-bucket pass.

#define HF 64          // feature width
#define BSH 9          // bucket shift: 512 nodes per bucket
#define BSZ 512
#define PCHUNK 8192    // edges per k_part block
#define CAP 12288      // LDS out capacity in k_place2 (mean 8192, sigma ~90)

typedef unsigned u32;

// ---- generic zero ----------------------------------------------------------
__global__ __launch_bounds__(256) void k_zero(u32* __restrict__ p, int n) {
    int i = blockIdx.x * 256 + threadIdx.x;
    if (i < n) p[i] = 0u;
}

// ---- coarse bucket histogram (bucket = col >> BSH) -------------------------
__global__ __launch_bounds__(256) void k_bhist(const int* __restrict__ cols,
                                               u32* __restrict__ gbh, int E, int NB) {
    __shared__ u32 h[256];
    int tid = threadIdx.x;
    h[tid] = 0;
    __syncthreads();
    for (int i = blockIdx.x * 256 + tid; i < E; i += gridDim.x * 256)
        atomicAdd(&h[((u32)cols[i]) >> BSH], 1u);
    __syncthreads();
    if (tid < NB && h[tid]) atomicAdd(&gbh[tid], h[tid]);
}

// ---- bucket scan (one block; NB <= 256): bases + partition cursors ---------
__global__ __launch_bounds__(256) void k_bscan(const u32* __restrict__ gbh,
                                               u32* __restrict__ bscan,
                                               u32* __restrict__ gcurb, int NB, int E) {
    __shared__ u32 s[256];
    int tid = threadIdx.x;
    u32 v = (tid < NB) ? gbh[tid] : 0u;
    s[tid] = v;
    __syncthreads();
    for (int o = 1; o < 256; o <<= 1) {
        u32 t = (tid >= o) ? s[tid - o] : 0u;
        __syncthreads();
        s[tid] += t;
        __syncthreads();
    }
    u32 excl = s[tid] - v;
    if (tid < NB) { bscan[tid] = excl; gcurb[tid] = excl; }
    if (tid == 0) bscan[NB] = (u32)E;
}

// ---- partition: edges -> part[] grouped by coarse bucket, LDS-reordered ----
// part element packs (col & 511) << 17 | row  (N < 2^17).
__global__ __launch_bounds__(256) void k_part(const int* __restrict__ rows,
                                              const int* __restrict__ cols,
                                              u32* __restrict__ gcurb,
                                              u32* __restrict__ part, int E) {
    __shared__ u32 hist[256];
    __shared__ u32 off[256];
    __shared__ u32 obase[256];
    __shared__ u32 cur[256];
    __shared__ u32 sc[256];
    __shared__ u32 stage[PCHUNK];
    __shared__ unsigned char sbk[PCHUNK];
    const int tid = threadIdx.x;
    const int e0  = blockIdx.x * PCHUNK;
    u32 er[32], ec[32];

    hist[tid] = 0;
    __syncthreads();
#pragma unroll
    for (int j = 0; j < 32; ++j) {
        int e = e0 + j * 256 + tid;
        if (e < E) {
            ec[j] = (u32)cols[e];
            er[j] = (u32)rows[e];
            atomicAdd(&hist[ec[j] >> BSH], 1u);
        } else ec[j] = 0xFFFFFFFFu;
    }
    __syncthreads();
    u32 v = hist[tid];
    sc[tid] = v;
    __syncthreads();
    for (int o = 1; o < 256; o <<= 1) {
        u32 t = (tid >= o) ? sc[tid - o] : 0u;
        __syncthreads();
        sc[tid] += t;
        __syncthreads();
    }
    off[tid] = sc[tid] - v;  // chunk-local exclusive offset
    cur[tid] = sc[tid] - v;
    obase[tid] = v ? atomicAdd(&gcurb[tid], v) : 0u;  // reserve global range
    __syncthreads();
#pragma unroll
    for (int j = 0; j < 32; ++j) {
        if (ec[j] != 0xFFFFFFFFu) {
            u32 bk  = ec[j] >> BSH;
            u32 pos = atomicAdd(&cur[bk], 1u);
            stage[pos] = ((ec[j] & (BSZ - 1)) << 17) | er[j];
            sbk[pos]   = (unsigned char)bk;
        }
    }
    __syncthreads();
    const int total = (e0 + PCHUNK <= E) ? PCHUNK : (E - e0);
    for (int i = tid; i < total; i += 256) {
        u32 bk = sbk[i];
        part[obase[bk] + ((u32)i - off[bk])] = stage[i];  // coalesced runs
    }
}

// ---- per-bucket placement: node hist + scan + dis + rowptr + eidx in LDS ---
__global__ __launch_bounds__(256) void k_place2(const u32* __restrict__ bscan,
                                                const u32* __restrict__ part,
                                                u32* __restrict__ rowptr,
                                                float* __restrict__ dis,
                                                int* __restrict__ eidx, int N) {
    __shared__ u32 cnt_[512];
    __shared__ u32 off_[513];
    __shared__ u32 sc[256];
    __shared__ u32 cur[512];
    __shared__ u32 outb[CAP];
    const int tid = threadIdx.x;
    const int b   = blockIdx.x;
    const int n0  = b << BSH;
    const u32 base = bscan[b];
    const u32 cntB = bscan[b + 1] - base;

    cnt_[tid] = 0; cnt_[tid + 256] = 0;
    __syncthreads();
    for (u32 i = tid; i < cntB; i += 256)
        atomicAdd(&cnt_[part[base + i] >> 17], 1u);
    __syncthreads();
    // exclusive scan of 512 counts (2 per thread)
    u32 c0 = cnt_[2 * tid], c1 = cnt_[2 * tid + 1];
    u32 s = c0 + c1;
    sc[tid] = s;
    __syncthreads();
    for (int o = 1; o < 256; o <<= 1) {
        u32 t = (tid >= o) ? sc[tid - o] : 0u;
        __syncthreads();
        sc[tid] += t;
        __syncthreads();
    }
    u32 ex = sc[tid] - s;
    off_[2 * tid] = ex;        cur[2 * tid] = ex;
    off_[2 * tid + 1] = ex + c0; cur[2 * tid + 1] = ex + c0;
    if (tid == 0) off_[512] = cntB;
    __syncthreads();
    // rowptr (exclusive start) + dis, coalesced
    for (int j = tid; j < 512; j += 256) {
        int n = n0 + j;
        if (n < N) {
            rowptr[n] = base + off_[j];
            dis[n]    = rsqrtf(1.0f + (float)cnt_[j]);
        }
    }
    if (cntB <= CAP) {
        for (u32 i = tid; i < cntB; i += 256) {
            u32 p   = part[base + i];
            u32 pos = atomicAdd(&cur[p >> 17], 1u);
            outb[pos] = p & 0x1FFFFu;
        }
        __syncthreads();
        for (u32 i = tid; i < cntB; i += 256)
            eidx[base + i] = (int)outb[i];  // coalesced stream
    } else {
        // multi-pass fallback over node sub-ranges (never expected for this input)
        int j0 = 0;
        while (j0 < 512) {
            int j1 = j0 + 1;
            while (j1 < 512 && off_[j1 + 1] - off_[j0] <= CAP) ++j1;
            u32 p0 = off_[j0], p1 = off_[j1];
            for (u32 i = tid; i < cntB; i += 256) {
                u32 p  = part[base + i];
                u32 lc = p >> 17;
                if (lc >= (u32)j0 && lc < (u32)j1) {
                    u32 pos = atomicAdd(&cur[lc], 1u);
                    outb[pos - p0] = p & 0x1FFFFu;
                }
            }
            __syncthreads();
            for (u32 i = tid; i < p1 - p0; i += 256)
                eidx[base + p0 + i] = (int)outb[i];
            __syncthreads();
            j0 = j1;
        }
    }
}

// ---- dense transform: OUT[N,64] = act(X[N,64]) @ W[64,64] ------------------
template <int RELU_IN>
__global__ __launch_bounds__(256) void k_gemm64(const float* __restrict__ X,
                                                const float* __restrict__ W,
                                                float* __restrict__ OUT, int N) {
    __shared__ float ws[64 * 64];
    __shared__ float xs[64 * 68];
    const int tid  = threadIdx.x;
    const int row0 = blockIdx.x * 64;

#pragma unroll
    for (int i = 0; i < 4; ++i) {
        int idx4 = i * 256 + tid;
        *(float4*)&ws[idx4 * 4] = ((const float4*)W)[idx4];
    }
#pragma unroll
    for (int i = 0; i < 4; ++i) {
        int idx4 = i * 256 + tid;
        int r    = idx4 >> 4;
        int kk   = (idx4 & 15) << 2;
        float4 v = float4{0.f, 0.f, 0.f, 0.f};
        int row  = row0 + r;
        if (row < N) v = ((const float4*)(X + (size_t)row * HF))[idx4 & 15];
        if (RELU_IN) {
            v.x = fmaxf(v.x, 0.f); v.y = fmaxf(v.y, 0.f);
            v.z = fmaxf(v.z, 0.f); v.w = fmaxf(v.w, 0.f);
        }
        *(float4*)&xs[r * 68 + kk] = v;
    }
    __syncthreads();

    const int rg = tid >> 4;
    const int cg = tid & 15;
    float4 a0 = float4{0.f, 0.f, 0.f, 0.f};
    float4 a1 = a0, a2 = a0, a3 = a0;

#pragma unroll
    for (int k = 0; k < 64; ++k) {
        float4 wv = *(float4*)&ws[k * 64 + cg * 4];
        float  x0 = xs[(rg * 4 + 0) * 68 + k];
        float  x1 = xs[(rg * 4 + 1) * 68 + k];
        float  x2 = xs[(rg * 4 + 2) * 68 + k];
        float  x3 = xs[(rg * 4 + 3) * 68 + k];
        a0.x += x0 * wv.x; a0.y += x0 * wv.y; a0.z += x0 * wv.z; a0.w += x0 * wv.w;
        a1.x += x1 * wv.x; a1.y += x1 * wv.y; a1.z += x1 * wv.z; a1.w += x1 * wv.w;
        a2.x += x2 * wv.x; a2.y += x2 * wv.y; a2.z += x2 * wv.z; a2.w += x2 * wv.w;
        a3.x += x3 * wv.x; a3.y += x3 * wv.y; a3.z += x3 * wv.z; a3.w += x3 * wv.w;
    }

    float4 accs[4] = {a0, a1, a2, a3};
#pragma unroll
    for (int j = 0; j < 4; ++j) {
        int row = row0 + rg * 4 + j;
        if (row < N) *(float4*)&OUT[(size_t)row * HF + cg * 4] = accs[j];
    }
}

// ---- CSR gather aggregation ------------------------------------------------
// agg[n] = dis[n] * ( sum_{r in nbrs(n)} dis[r]*h[r] + dis[n]*h[n] ) + b
__global__ __launch_bounds__(256) void k_gather(const u32* __restrict__ rowptr,
                                                const int* __restrict__ eidx,
                                                const float* __restrict__ dis,
                                                const float* __restrict__ h,
                                                const float* __restrict__ b,
                                                float* __restrict__ agg, int N, int E) {
    const int lane = threadIdx.x & 63;
    const int n    = blockIdx.x * 4 + (threadIdx.x >> 6);
    if (n >= N) return;
    u32 start = rowptr[n];
    u32 end   = (n + 1 < N) ? rowptr[n + 1] : (u32)E;
    float dn  = dis[n];
    float acc = 0.f;
    u32 e = start;
    for (; e + 2 <= end; e += 2) {
        int r0 = eidx[e], r1 = eidx[e + 1];
        float d0 = dis[r0], d1 = dis[r1];
        float h0 = h[(size_t)r0 * HF + lane];
        float h1 = h[(size_t)r1 * HF + lane];
        acc += d0 * h0 + d1 * h1;
    }
    if (e < end) {
        int r = eidx[e];
        acc += dis[r] * h[(size_t)r * HF + lane];
    }
    acc += dn * h[(size_t)n * HF + lane];  // self-loop
    agg[(size_t)n * HF + lane] = dn * acc + b[lane];
}

// ---- pooling (batch_index sorted: run-length, few atomics) -----------------
__global__ __launch_bounds__(256) void k_pool(const float* __restrict__ agg,
                                              const int* __restrict__ batch,
                                              float* __restrict__ sums,
                                              float* __restrict__ cnt, int N) {
    const int NODES_PER_WAVE = 256;
    const int lane = threadIdx.x & 63;
    const int wid  = blockIdx.x * 4 + (threadIdx.x >> 6);
    int start = wid * NODES_PER_WAVE;
    if (start >= N) return;
    int end = min(start + NODES_PER_WAVE, N);
    int cur = batch[start];
    float acc = 0.f, cc = 0.f;
    for (int n = start; n < end; ++n) {
        int b = batch[n];
        if (b != cur) {
            atomicAdd(&sums[cur * HF + lane], acc);
            if (lane == 0) atomicAdd(&cnt[cur], cc);
            acc = 0.f; cc = 0.f; cur = b;
        }
        acc += fmaxf(agg[(size_t)n * HF + lane], 0.f);  // relu fused
        cc  += 1.f;
    }
    atomicAdd(&sums[cur * HF + lane], acc);
    if (lane == 0) atomicAdd(&cnt[cur], cc);
}

// ---- MLP head --------------------------------------------------------------
__global__ __launch_bounds__(256) void k_head1(const float* __restrict__ sums,
                                               const float* __restrict__ cnt,
                                               const float* __restrict__ Wl1,
                                               const float* __restrict__ bl1,
                                               float* __restrict__ hid) {
    int tid = threadIdx.x;
    int g   = blockIdx.x * 8 + (tid >> 5);
    int j   = tid & 31;
    float rinv = 1.0f / fmaxf(cnt[g], 1.0f);
    float a = bl1[j];
#pragma unroll
    for (int k = 0; k < 64; ++k)
        a += (sums[g * HF + k] * rinv) * Wl1[k * 32 + j];
    hid[g * 32 + j] = fmaxf(a, 0.f);
}

__global__ __launch_bounds__(256) void k_head2(const float* __restrict__ hid,
                                               const float* __restrict__ Wl2,
                                               const float* __restrict__ bl2,
                                               float* __restrict__ out) {
    int g = threadIdx.x;
    float l0 = bl2[0], l1 = bl2[1];
#pragma unroll
    for (int j = 0; j < 32; ++j) {
        float hv = hid[g * 32 + j];
        l0 += hv * Wl2[2 * j];
        l1 += hv * Wl2[2 * j + 1];
    }
    float m   = fmaxf(l0, l1);
    float lse = m + logf(expf(l0 - m) + expf(l1 - m));
    out[2 * g]     = l0 - lse;
    out[2 * g + 1] = l1 - lse;
}

// ---- driver ----------------------------------------------------------------
extern "C" void kernel_launch(void* const* d_in, const int* in_sizes, int n_in,
                              void* d_out, int out_size, void* d_ws, size_t ws_size,
                              hipStream_t stream) {
    const float* x   = (const float*)d_in[0];
    const int*   ei  = (const int*)d_in[1];
    const int*   bi  = (const int*)d_in[2];
    const float* W1  = (const float*)d_in[3];
    const float* b1  = (const float*)d_in[4];
    const float* W2  = (const float*)d_in[5];
    const float* b2  = (const float*)d_in[6];
    const float* Wl1 = (const float*)d_in[7];
    const float* bl1 = (const float*)d_in[8];
    const float* Wl2 = (const float*)d_in[9];
    const float* bl2 = (const float*)d_in[10];
    float* out = (float*)d_out;

    const int N = in_sizes[0] / HF;
    const int E = in_sizes[1] / 2;
    const int* rows = ei;       // edge_index[0] = sources
    const int* cols = ei + E;   // edge_index[1] = targets
    const int NB = (N + BSZ - 1) / BSZ;  // coarse buckets (<=256)

    // workspace layout (4B units); part[] aliases agg (dead before gather).
    float* ws = (float*)d_ws;
    size_t o = 0;
    float* dis    = ws + o; o += ((size_t)N + 63) / 64 * 64;
    float* h      = ws + o; o += (size_t)N * HF;
    float* agg    = ws + o; o += (size_t)N * HF;
    u32*   part   = (u32*)agg;                       // E u32, alias
    u32*   rowptr = (u32*)(ws + o); o += ((size_t)N + 63) / 64 * 64;
    int*   eidx   = (int*)(ws + o); o += (size_t)E;
    u32*   gbh    = (u32*)(ws + o); o += 256;
    u32*   bscan  = (u32*)(ws + o); o += 320;
    u32*   gcurb  = (u32*)(ws + o); o += 256;
    float* sums   = ws + o; o += 256 * HF;
    float* cnt    = ws + o; o += 256;
    float* hid    = ws + o; o += 256 * 32;

    const int gb = (N + 63) / 64;

    // CSR build (two-level bucket sort; shared by both layers)
    k_zero<<<1, 256, 0, stream>>>(gbh, 256);
    k_bhist<<<256, 256, 0, stream>>>(cols, gbh, E, NB);
    k_bscan<<<1, 256, 0, stream>>>(gbh, bscan, gcurb, NB, E);
    k_part<<<(E + PCHUNK - 1) / PCHUNK, 256, 0, stream>>>(rows, cols, gcurb, part, E);
    k_place2<<<NB, 256, 0, stream>>>(bscan, part, rowptr, dis, eidx, N);

    // layer 1
    k_gemm64<0><<<gb, 256, 0, stream>>>(x, W1, h, N);
    k_gather<<<(N + 3) / 4, 256, 0, stream>>>(rowptr, eidx, dis, h, b1, agg, N, E);

    // layer 2
    k_gemm64<1><<<gb, 256, 0, stream>>>(agg, W2, h, N);
    k_gather<<<(N + 3) / 4, 256, 0, stream>>>(rowptr, eidx, dis, h, b2, agg, N, E);

    // mean pool (relu fused) + head
    k_zero<<<(256 * HF + 256 + 255) / 256, 256, 0, stream>>>((u32*)sums, 256 * HF + 256);
    {
        int pw = (N + 255) / 256;
        int pb = (pw + 3) / 4;
        k_pool<<<pb, 256, 0, stream>>>(agg, bi, sums, cnt, N);
    }
    k_head1<<<32, 256, 0, stream>>>(sums, cnt, Wl1, bl1, hid);
    k_head2<<<1, 256, 0, stream>>>(hid, Wl2, bl2, out);
}

// Round 4
// 404.211 us; speedup vs baseline: 2.5847x; 1.2730x over previous
//
#include <hip/hip_runtime.h>
#include <cstdint>
#include <cstddef>

// GCN: h1 = relu(Â (x W1) + b1); h2 = relu(Â (h1 W2) + b2);
// g = mean-pool(h2 by batch); out = log_softmax(relu(g Wl1 + bl1) Wl2 + bl2)
// Â = D^-1/2 (A + I) D^-1/2.
//
// R4: gather was 2x102us, FETCH 194MB (random 256B fp32 rows, 3 loads/edge).
// Now GEMM epilogue writes hs[r] = dis[r]*h[r] as packed bf16 (128B rows):
// gather needs no dis loads, half the bytes, and processes 2 edges/wave
// (two 32-lane halves, each gathering a full bf16 row). Pool is one block
// per graph (sorted batch -> binary search, no atomics); head is one fused
// block.

#define HF 64          // feature width
#define BSH 9          // bucket shift: 512 nodes per bucket
#define BSZ 512
#define PCHUNK 8192    // edges per k_part block
#define CAP 12288      // LDS out capacity in k_place2

typedef unsigned u32;

__device__ __forceinline__ unsigned short f2bf(float x) {
    unsigned u = __float_as_uint(x);
    unsigned r = (u + 0x7fffu + ((u >> 16) & 1u)) >> 16;   // RNE
    return (unsigned short)r;
}

// ---- generic zero ----------------------------------------------------------
__global__ __launch_bounds__(256) void k_zero(u32* __restrict__ p, int n) {
    int i = blockIdx.x * 256 + threadIdx.x;
    if (i < n) p[i] = 0u;
}

// ---- coarse bucket histogram (bucket = col >> BSH) -------------------------
__global__ __launch_bounds__(256) void k_bhist(const int* __restrict__ cols,
                                               u32* __restrict__ gbh, int E, int NB) {
    __shared__ u32 h[256];
    int tid = threadIdx.x;
    h[tid] = 0;
    __syncthreads();
    for (int i = blockIdx.x * 256 + tid; i < E; i += gridDim.x * 256)
        atomicAdd(&h[((u32)cols[i]) >> BSH], 1u);
    __syncthreads();
    if (tid < NB && h[tid]) atomicAdd(&gbh[tid], h[tid]);
}

// ---- bucket scan (one block; NB <= 256) ------------------------------------
__global__ __launch_bounds__(256) void k_bscan(const u32* __restrict__ gbh,
                                               u32* __restrict__ bscan,
                                               u32* __restrict__ gcurb, int NB, int E) {
    __shared__ u32 s[256];
    int tid = threadIdx.x;
    u32 v = (tid < NB) ? gbh[tid] : 0u;
    s[tid] = v;
    __syncthreads();
    for (int o = 1; o < 256; o <<= 1) {
        u32 t = (tid >= o) ? s[tid - o] : 0u;
        __syncthreads();
        s[tid] += t;
        __syncthreads();
    }
    u32 excl = s[tid] - v;
    if (tid < NB) { bscan[tid] = excl; gcurb[tid] = excl; }
    if (tid == 0) bscan[NB] = (u32)E;
}

// ---- partition: edges -> part[] grouped by coarse bucket, LDS-reordered ----
// part element packs (col & 511) << 17 | row  (N < 2^17).
__global__ __launch_bounds__(256) void k_part(const int* __restrict__ rows,
                                              const int* __restrict__ cols,
                                              u32* __restrict__ gcurb,
                                              u32* __restrict__ part, int E) {
    __shared__ u32 hist[256];
    __shared__ u32 off[256];
    __shared__ u32 obase[256];
    __shared__ u32 cur[256];
    __shared__ u32 sc[256];
    __shared__ u32 stage[PCHUNK];
    __shared__ unsigned char sbk[PCHUNK];
    const int tid = threadIdx.x;
    const int e0  = blockIdx.x * PCHUNK;
    u32 er[32], ec[32];

    hist[tid] = 0;
    __syncthreads();
#pragma unroll
    for (int j = 0; j < 32; ++j) {
        int e = e0 + j * 256 + tid;
        if (e < E) {
            ec[j] = (u32)cols[e];
            er[j] = (u32)rows[e];
            atomicAdd(&hist[ec[j] >> BSH], 1u);
        } else ec[j] = 0xFFFFFFFFu;
    }
    __syncthreads();
    u32 v = hist[tid];
    sc[tid] = v;
    __syncthreads();
    for (int o = 1; o < 256; o <<= 1) {
        u32 t = (tid >= o) ? sc[tid - o] : 0u;
        __syncthreads();
        sc[tid] += t;
        __syncthreads();
    }
    off[tid] = sc[tid] - v;
    cur[tid] = sc[tid] - v;
    obase[tid] = v ? atomicAdd(&gcurb[tid], v) : 0u;
    __syncthreads();
#pragma unroll
    for (int j = 0; j < 32; ++j) {
        if (ec[j] != 0xFFFFFFFFu) {
            u32 bk  = ec[j] >> BSH;
            u32 pos = atomicAdd(&cur[bk], 1u);
            stage[pos] = ((ec[j] & (BSZ - 1)) << 17) | er[j];
            sbk[pos]   = (unsigned char)bk;
        }
    }
    __syncthreads();
    const int total = (e0 + PCHUNK <= E) ? PCHUNK : (E - e0);
    for (int i = tid; i < total; i += 256) {
        u32 bk = sbk[i];
        part[obase[bk] + ((u32)i - off[bk])] = stage[i];
    }
}

// ---- per-bucket placement: node hist + scan + dis + rowptr + eidx in LDS ---
__global__ __launch_bounds__(256) void k_place2(const u32* __restrict__ bscan,
                                                const u32* __restrict__ part,
                                                u32* __restrict__ rowptr,
                                                float* __restrict__ dis,
                                                int* __restrict__ eidx, int N) {
    __shared__ u32 cnt_[512];
    __shared__ u32 off_[513];
    __shared__ u32 sc[256];
    __shared__ u32 cur[512];
    __shared__ u32 outb[CAP];
    const int tid = threadIdx.x;
    const int b   = blockIdx.x;
    const int n0  = b << BSH;
    const u32 base = bscan[b];
    const u32 cntB = bscan[b + 1] - base;

    cnt_[tid] = 0; cnt_[tid + 256] = 0;
    __syncthreads();
    for (u32 i = tid; i < cntB; i += 256)
        atomicAdd(&cnt_[part[base + i] >> 17], 1u);
    __syncthreads();
    u32 c0 = cnt_[2 * tid], c1 = cnt_[2 * tid + 1];
    u32 s = c0 + c1;
    sc[tid] = s;
    __syncthreads();
    for (int o = 1; o < 256; o <<= 1) {
        u32 t = (tid >= o) ? sc[tid - o] : 0u;
        __syncthreads();
        sc[tid] += t;
        __syncthreads();
    }
    u32 ex = sc[tid] - s;
    off_[2 * tid] = ex;          cur[2 * tid] = ex;
    off_[2 * tid + 1] = ex + c0; cur[2 * tid + 1] = ex + c0;
    if (tid == 0) off_[512] = cntB;
    __syncthreads();
    for (int j = tid; j < 512; j += 256) {
        int n = n0 + j;
        if (n < N) {
            rowptr[n] = base + off_[j];
            dis[n]    = rsqrtf(1.0f + (float)cnt_[j]);
        }
    }
    if (cntB <= CAP) {
        for (u32 i = tid; i < cntB; i += 256) {
            u32 p   = part[base + i];
            u32 pos = atomicAdd(&cur[p >> 17], 1u);
            outb[pos] = p & 0x1FFFFu;
        }
        __syncthreads();
        for (u32 i = tid; i < cntB; i += 256)
            eidx[base + i] = (int)outb[i];
    } else {
        int j0 = 0;
        while (j0 < 512) {
            int j1 = j0 + 1;
            while (j1 < 512 && off_[j1 + 1] - off_[j0] <= CAP) ++j1;
            u32 p0 = off_[j0], p1 = off_[j1];
            for (u32 i = tid; i < cntB; i += 256) {
                u32 p  = part[base + i];
                u32 lc = p >> 17;
                if (lc >= (u32)j0 && lc < (u32)j1) {
                    u32 pos = atomicAdd(&cur[lc], 1u);
                    outb[pos - p0] = p & 0x1FFFFu;
                }
            }
            __syncthreads();
            for (u32 i = tid; i < p1 - p0; i += 256)
                eidx[base + p0 + i] = (int)outb[i];
            __syncthreads();
            j0 = j1;
        }
    }
}

// ---- dense transform: HS[N,64](bf16) = dis[n] * (act(X[N,64]) @ W[64,64]) --
template <int RELU_IN>
__global__ __launch_bounds__(256) void k_gemm(const float* __restrict__ X,
                                              const float* __restrict__ W,
                                              const float* __restrict__ dis,
                                              unsigned short* __restrict__ HS, int N) {
    __shared__ float ws[64 * 64];
    __shared__ float xs[64 * 68];
    const int tid  = threadIdx.x;
    const int row0 = blockIdx.x * 64;

#pragma unroll
    for (int i = 0; i < 4; ++i) {
        int idx4 = i * 256 + tid;
        *(float4*)&ws[idx4 * 4] = ((const float4*)W)[idx4];
    }
#pragma unroll
    for (int i = 0; i < 4; ++i) {
        int idx4 = i * 256 + tid;
        int r    = idx4 >> 4;
        int kk   = (idx4 & 15) << 2;
        float4 v = float4{0.f, 0.f, 0.f, 0.f};
        int row  = row0 + r;
        if (row < N) v = ((const float4*)(X + (size_t)row * HF))[idx4 & 15];
        if (RELU_IN) {
            v.x = fmaxf(v.x, 0.f); v.y = fmaxf(v.y, 0.f);
            v.z = fmaxf(v.z, 0.f); v.w = fmaxf(v.w, 0.f);
        }
        *(float4*)&xs[r * 68 + kk] = v;
    }
    __syncthreads();

    const int rg = tid >> 4;
    const int cg = tid & 15;
    float4 a0 = float4{0.f, 0.f, 0.f, 0.f};
    float4 a1 = a0, a2 = a0, a3 = a0;

#pragma unroll
    for (int k = 0; k < 64; ++k) {
        float4 wv = *(float4*)&ws[k * 64 + cg * 4];
        float  x0 = xs[(rg * 4 + 0) * 68 + k];
        float  x1 = xs[(rg * 4 + 1) * 68 + k];
        float  x2 = xs[(rg * 4 + 2) * 68 + k];
        float  x3 = xs[(rg * 4 + 3) * 68 + k];
        a0.x += x0 * wv.x; a0.y += x0 * wv.y; a0.z += x0 * wv.z; a0.w += x0 * wv.w;
        a1.x += x1 * wv.x; a1.y += x1 * wv.y; a1.z += x1 * wv.z; a1.w += x1 * wv.w;
        a2.x += x2 * wv.x; a2.y += x2 * wv.y; a2.z += x2 * wv.z; a2.w += x2 * wv.w;
        a3.x += x3 * wv.x; a3.y += x3 * wv.y; a3.z += x3 * wv.z; a3.w += x3 * wv.w;
    }

    float4 accs[4] = {a0, a1, a2, a3};
#pragma unroll
    for (int j = 0; j < 4; ++j) {
        int row = row0 + rg * 4 + j;
        if (row < N) {
            float d = dis[row];
            float4 a = accs[j];
            ushort4 pk;
            pk.x = f2bf(d * a.x); pk.y = f2bf(d * a.y);
            pk.z = f2bf(d * a.z); pk.w = f2bf(d * a.w);
            *(ushort4*)&HS[(size_t)row * HF + cg * 4] = pk;
        }
    }
}

// ---- CSR gather aggregation (bf16 pre-scaled rows) -------------------------
// agg[n] = dis[n] * ( sum_{r in nbrs(n)} hs[r] + hs[n] ) + b
// One wave per node; two 32-lane halves each gather a full 128B bf16 row.
__global__ __launch_bounds__(256) void k_gather(const u32* __restrict__ rowptr,
                                                const int* __restrict__ eidx,
                                                const float* __restrict__ dis,
                                                const u32* __restrict__ hs,  // bf16 pairs
                                                const float* __restrict__ b,
                                                float* __restrict__ agg, int N, int E) {
    const int tid  = threadIdx.x;
    const int lane = tid & 63;
    const int half = lane >> 5;
    const int f2   = lane & 31;      // feature pair: feats 2*f2, 2*f2+1
    const int n    = blockIdx.x * 4 + (tid >> 6);
    if (n >= N) return;
    u32 start = rowptr[n];
    u32 end   = (n + 1 < N) ? rowptr[n + 1] : (u32)E;
    float ax = 0.f, ay = 0.f;

    u32 e = start + half;
    for (; e + 2 < end; e += 4) {            // 2 edges per half per iter
        int r0 = eidx[e], r1 = eidx[e + 2];
        u32 w0 = hs[(size_t)r0 * 32 + f2];
        u32 w1 = hs[(size_t)r1 * 32 + f2];
        ax += __uint_as_float(w0 << 16) + __uint_as_float(w1 << 16);
        ay += __uint_as_float(w0 & 0xffff0000u) + __uint_as_float(w1 & 0xffff0000u);
    }
    if (e < end) {
        int r = eidx[e];
        u32 w = hs[(size_t)r * 32 + f2];
        ax += __uint_as_float(w << 16);
        ay += __uint_as_float(w & 0xffff0000u);
    }
    if (half == 0) {                          // self-loop
        u32 w = hs[(size_t)n * 32 + f2];
        ax += __uint_as_float(w << 16);
        ay += __uint_as_float(w & 0xffff0000u);
    }
    ax += __shfl_xor(ax, 32);
    ay += __shfl_xor(ay, 32);
    if (lane < 32) {
        float dn = dis[n];
        float2 bv = ((const float2*)b)[f2];
        float2 o;
        o.x = dn * ax + bv.x;
        o.y = dn * ay + bv.y;
        ((float2*)(agg + (size_t)n * HF))[f2] = o;
    }
}

// ---- pooling: one block per graph (batch sorted), relu fused, no atomics ---
__device__ __forceinline__ int lower_bound(const int* __restrict__ a, int n, int key) {
    int lo = 0, hi = n;
    while (lo < hi) { int mid = (lo + hi) >> 1; if (a[mid] < key) lo = mid + 1; else hi = mid; }
    return lo;
}

__global__ __launch_bounds__(256) void k_pool(const float* __restrict__ agg,
                                              const int* __restrict__ batch,
                                              float* __restrict__ gmean, int N) {
    __shared__ float red[4][64];
    const int g    = blockIdx.x;
    const int lane = threadIdx.x & 63;
    const int w    = threadIdx.x >> 6;
    int s = lower_bound(batch, N, g);
    int e = lower_bound(batch, N, g + 1);
    float acc = 0.f;
    for (int n = s + w; n < e; n += 4)
        acc += fmaxf(agg[(size_t)n * HF + lane], 0.f);
    red[w][lane] = acc;
    __syncthreads();
    if (w == 0) {
        float t = red[0][lane] + red[1][lane] + red[2][lane] + red[3][lane];
        gmean[g * HF + lane] = t / fmaxf((float)(e - s), 1.0f);
    }
}

// ---- fused MLP head (one block; thread = graph) ----------------------------
__global__ __launch_bounds__(256) void k_head(const float* __restrict__ gmean,
                                              const float* __restrict__ Wl1,
                                              const float* __restrict__ bl1,
                                              const float* __restrict__ Wl2,
                                              const float* __restrict__ bl2,
                                              float* __restrict__ out) {
    __shared__ float w1[64 * 32];
    __shared__ float w2[64];
    __shared__ float bb1[32];
    const int tid = threadIdx.x;
    for (int i = tid; i < 64 * 32; i += 256) w1[i] = Wl1[i];
    if (tid < 64) w2[tid] = Wl2[tid];
    if (tid < 32) bb1[tid] = bl1[tid];
    __syncthreads();

    const int g = tid;  // 256 graphs
    float gm[64];
#pragma unroll
    for (int k = 0; k < 64; ++k) gm[k] = gmean[g * HF + k];
    float l0 = bl2[0], l1 = bl2[1];
#pragma unroll
    for (int j = 0; j < 32; ++j) {
        float a = bb1[j];
#pragma unroll
        for (int k = 0; k < 64; ++k) a += gm[k] * w1[k * 32 + j];
        a = fmaxf(a, 0.f);
        l0 += a * w2[2 * j];
        l1 += a * w2[2 * j + 1];
    }
    float m   = fmaxf(l0, l1);
    float lse = m + logf(expf(l0 - m) + expf(l1 - m));
    out[2 * g]     = l0 - lse;
    out[2 * g + 1] = l1 - lse;
}

// ---- driver ----------------------------------------------------------------
extern "C" void kernel_launch(void* const* d_in, const int* in_sizes, int n_in,
                              void* d_out, int out_size, void* d_ws, size_t ws_size,
                              hipStream_t stream) {
    const float* x   = (const float*)d_in[0];
    const int*   ei  = (const int*)d_in[1];
    const int*   bi  = (const int*)d_in[2];
    const float* W1  = (const float*)d_in[3];
    const float* b1  = (const float*)d_in[4];
    const float* W2  = (const float*)d_in[5];
    const float* b2  = (const float*)d_in[6];
    const float* Wl1 = (const float*)d_in[7];
    const float* bl1 = (const float*)d_in[8];
    const float* Wl2 = (const float*)d_in[9];
    const float* bl2 = (const float*)d_in[10];
    float* out = (float*)d_out;

    const int N = in_sizes[0] / HF;
    const int E = in_sizes[1] / 2;
    const int* rows = ei;
    const int* cols = ei + E;
    const int NB = (N + BSZ - 1) / BSZ;

    // workspace (4B units); part[] aliases agg (dead before first gather).
    float* ws = (float*)d_ws;
    size_t o = 0;
    float* dis    = ws + o; o += ((size_t)N + 63) / 64 * 64;
    unsigned short* hs = (unsigned short*)(ws + o); o += (size_t)N * 32;  // bf16 N x 64
    float* agg    = ws + o; o += (size_t)N * HF;
    u32*   part   = (u32*)agg;
    u32*   rowptr = (u32*)(ws + o); o += ((size_t)N + 63) / 64 * 64;
    int*   eidx   = (int*)(ws + o); o += (size_t)E;
    u32*   gbh    = (u32*)(ws + o); o += 256;
    u32*   bscan  = (u32*)(ws + o); o += 320;
    u32*   gcurb  = (u32*)(ws + o); o += 256;
    float* gmean  = ws + o; o += 256 * HF;

    const int gb = (N + 63) / 64;

    // CSR build (two-level bucket sort; shared by both layers)
    k_zero<<<1, 256, 0, stream>>>(gbh, 256);
    k_bhist<<<256, 256, 0, stream>>>(cols, gbh, E, NB);
    k_bscan<<<1, 256, 0, stream>>>(gbh, bscan, gcurb, NB, E);
    k_part<<<(E + PCHUNK - 1) / PCHUNK, 256, 0, stream>>>(rows, cols, gcurb, part, E);
    k_place2<<<NB, 256, 0, stream>>>(bscan, part, rowptr, dis, eidx, N);

    // layer 1
    k_gemm<0><<<gb, 256, 0, stream>>>(x, W1, dis, hs, N);
    k_gather<<<(N + 3) / 4, 256, 0, stream>>>(rowptr, eidx, dis, (const u32*)hs, b1, agg, N, E);

    // layer 2
    k_gemm<1><<<gb, 256, 0, stream>>>(agg, W2, dis, hs, N);
    k_gather<<<(N + 3) / 4, 256, 0, stream>>>(rowptr, eidx, dis, (const u32*)hs, b2, agg, N, E);

    // mean pool (relu fused) + fused head
    k_pool<<<256, 256, 0, stream>>>(agg, bi, gmean, N);
    k_head<<<1, 256, 0, stream>>>(gmean, Wl1, bl1, Wl2, bl2, out);
}

// Round 5
// 374.341 us; speedup vs baseline: 2.7909x; 1.0798x over previous
//
#include <hip/hip_runtime.h>
#include <cstdint>
#include <cstddef>

// GCN: h1 = relu(Â (x W1) + b1); h2 = relu(Â (h1 W2) + b2);
// g = mean-pool(h2 by batch); out = log_softmax(relu(g Wl1 + bl1) Wl2 + bl2)
// Â = D^-1/2 (A + I) D^-1/2.
//
// R5: (a) layer-2 dense transform fused into gather1 epilogue (row is
// wave-resident after the reduce; W2 staged in LDS) -- deletes k_gemm2 and
// its 51MB agg round-trip. (b) gather uses quarter-waves (16 lanes x uint2
// = one 128B bf16 row per quarter; 4 edges/wave-instr, unroll 2). (c) gather2
// writes relu'd agg as bf16; pool reads bf16.

#define HF 64          // feature width
#define BSH 9          // bucket shift: 512 nodes per bucket
#define BSZ 512
#define PCHUNK 8192    // edges per k_part block
#define CAP 12288      // LDS out capacity in k_place2

typedef unsigned u32;

__device__ __forceinline__ unsigned short f2bf(float x) {
    unsigned u = __float_as_uint(x);
    unsigned r = (u + 0x7fffu + ((u >> 16) & 1u)) >> 16;   // RNE
    return (unsigned short)r;
}
__device__ __forceinline__ float bfl(u32 w) { return __uint_as_float(w << 16); }
__device__ __forceinline__ float bfh(u32 w) { return __uint_as_float(w & 0xffff0000u); }

// ---- generic zero ----------------------------------------------------------
__global__ __launch_bounds__(256) void k_zero(u32* __restrict__ p, int n) {
    int i = blockIdx.x * 256 + threadIdx.x;
    if (i < n) p[i] = 0u;
}

// ---- coarse bucket histogram (bucket = col >> BSH) -------------------------
__global__ __launch_bounds__(256) void k_bhist(const int* __restrict__ cols,
                                               u32* __restrict__ gbh, int E, int NB) {
    __shared__ u32 h[256];
    int tid = threadIdx.x;
    h[tid] = 0;
    __syncthreads();
    for (int i = blockIdx.x * 256 + tid; i < E; i += gridDim.x * 256)
        atomicAdd(&h[((u32)cols[i]) >> BSH], 1u);
    __syncthreads();
    if (tid < NB && h[tid]) atomicAdd(&gbh[tid], h[tid]);
}

// ---- bucket scan (one block; NB <= 256) ------------------------------------
__global__ __launch_bounds__(256) void k_bscan(const u32* __restrict__ gbh,
                                               u32* __restrict__ bscan,
                                               u32* __restrict__ gcurb, int NB, int E) {
    __shared__ u32 s[256];
    int tid = threadIdx.x;
    u32 v = (tid < NB) ? gbh[tid] : 0u;
    s[tid] = v;
    __syncthreads();
    for (int o = 1; o < 256; o <<= 1) {
        u32 t = (tid >= o) ? s[tid - o] : 0u;
        __syncthreads();
        s[tid] += t;
        __syncthreads();
    }
    u32 excl = s[tid] - v;
    if (tid < NB) { bscan[tid] = excl; gcurb[tid] = excl; }
    if (tid == 0) bscan[NB] = (u32)E;
}

// ---- partition: edges -> part[] grouped by coarse bucket, LDS-reordered ----
// part element packs (col & 511) << 17 | row  (N < 2^17).
__global__ __launch_bounds__(256) void k_part(const int* __restrict__ rows,
                                              const int* __restrict__ cols,
                                              u32* __restrict__ gcurb,
                                              u32* __restrict__ part, int E) {
    __shared__ u32 hist[256];
    __shared__ u32 off[256];
    __shared__ u32 obase[256];
    __shared__ u32 cur[256];
    __shared__ u32 sc[256];
    __shared__ u32 stage[PCHUNK];
    __shared__ unsigned char sbk[PCHUNK];
    const int tid = threadIdx.x;
    const int e0  = blockIdx.x * PCHUNK;
    u32 er[32], ec[32];

    hist[tid] = 0;
    __syncthreads();
#pragma unroll
    for (int j = 0; j < 32; ++j) {
        int e = e0 + j * 256 + tid;
        if (e < E) {
            ec[j] = (u32)cols[e];
            er[j] = (u32)rows[e];
            atomicAdd(&hist[ec[j] >> BSH], 1u);
        } else ec[j] = 0xFFFFFFFFu;
    }
    __syncthreads();
    u32 v = hist[tid];
    sc[tid] = v;
    __syncthreads();
    for (int o = 1; o < 256; o <<= 1) {
        u32 t = (tid >= o) ? sc[tid - o] : 0u;
        __syncthreads();
        sc[tid] += t;
        __syncthreads();
    }
    off[tid] = sc[tid] - v;
    cur[tid] = sc[tid] - v;
    obase[tid] = v ? atomicAdd(&gcurb[tid], v) : 0u;
    __syncthreads();
#pragma unroll
    for (int j = 0; j < 32; ++j) {
        if (ec[j] != 0xFFFFFFFFu) {
            u32 bk  = ec[j] >> BSH;
            u32 pos = atomicAdd(&cur[bk], 1u);
            stage[pos] = ((ec[j] & (BSZ - 1)) << 17) | er[j];
            sbk[pos]   = (unsigned char)bk;
        }
    }
    __syncthreads();
    const int total = (e0 + PCHUNK <= E) ? PCHUNK : (E - e0);
    for (int i = tid; i < total; i += 256) {
        u32 bk = sbk[i];
        part[obase[bk] + ((u32)i - off[bk])] = stage[i];
    }
}

// ---- per-bucket placement: node hist + scan + dis + rowptr + eidx in LDS ---
__global__ __launch_bounds__(256) void k_place2(const u32* __restrict__ bscan,
                                                const u32* __restrict__ part,
                                                u32* __restrict__ rowptr,
                                                float* __restrict__ dis,
                                                int* __restrict__ eidx, int N) {
    __shared__ u32 cnt_[512];
    __shared__ u32 off_[513];
    __shared__ u32 sc[256];
    __shared__ u32 cur[512];
    __shared__ u32 outb[CAP];
    const int tid = threadIdx.x;
    const int b   = blockIdx.x;
    const int n0  = b << BSH;
    const u32 base = bscan[b];
    const u32 cntB = bscan[b + 1] - base;

    cnt_[tid] = 0; cnt_[tid + 256] = 0;
    __syncthreads();
    for (u32 i = tid; i < cntB; i += 256)
        atomicAdd(&cnt_[part[base + i] >> 17], 1u);
    __syncthreads();
    u32 c0 = cnt_[2 * tid], c1 = cnt_[2 * tid + 1];
    u32 s = c0 + c1;
    sc[tid] = s;
    __syncthreads();
    for (int o = 1; o < 256; o <<= 1) {
        u32 t = (tid >= o) ? sc[tid - o] : 0u;
        __syncthreads();
        sc[tid] += t;
        __syncthreads();
    }
    u32 ex = sc[tid] - s;
    off_[2 * tid] = ex;          cur[2 * tid] = ex;
    off_[2 * tid + 1] = ex + c0; cur[2 * tid + 1] = ex + c0;
    if (tid == 0) off_[512] = cntB;
    __syncthreads();
    for (int j = tid; j < 512; j += 256) {
        int n = n0 + j;
        if (n < N) {
            rowptr[n] = base + off_[j];
            dis[n]    = rsqrtf(1.0f + (float)cnt_[j]);
        }
    }
    if (cntB <= CAP) {
        for (u32 i = tid; i < cntB; i += 256) {
            u32 p   = part[base + i];
            u32 pos = atomicAdd(&cur[p >> 17], 1u);
            outb[pos] = p & 0x1FFFFu;
        }
        __syncthreads();
        for (u32 i = tid; i < cntB; i += 256)
            eidx[base + i] = (int)outb[i];
    } else {
        int j0 = 0;
        while (j0 < 512) {
            int j1 = j0 + 1;
            while (j1 < 512 && off_[j1 + 1] - off_[j0] <= CAP) ++j1;
            u32 p0 = off_[j0], p1 = off_[j1];
            for (u32 i = tid; i < cntB; i += 256) {
                u32 p  = part[base + i];
                u32 lc = p >> 17;
                if (lc >= (u32)j0 && lc < (u32)j1) {
                    u32 pos = atomicAdd(&cur[lc], 1u);
                    outb[pos - p0] = p & 0x1FFFFu;
                }
            }
            __syncthreads();
            for (u32 i = tid; i < p1 - p0; i += 256)
                eidx[base + p0 + i] = (int)outb[i];
            __syncthreads();
            j0 = j1;
        }
    }
}

// ---- layer-1 dense: HS[N,64](bf16) = dis[n] * (X[N,64] @ W[64,64]) ---------
__global__ __launch_bounds__(256) void k_gemm1(const float* __restrict__ X,
                                               const float* __restrict__ W,
                                               const float* __restrict__ dis,
                                               unsigned short* __restrict__ HS, int N) {
    __shared__ float ws[64 * 64];
    __shared__ float xs[64 * 68];
    const int tid  = threadIdx.x;
    const int row0 = blockIdx.x * 64;

#pragma unroll
    for (int i = 0; i < 4; ++i) {
        int idx4 = i * 256 + tid;
        *(float4*)&ws[idx4 * 4] = ((const float4*)W)[idx4];
    }
#pragma unroll
    for (int i = 0; i < 4; ++i) {
        int idx4 = i * 256 + tid;
        int r    = idx4 >> 4;
        int kk   = (idx4 & 15) << 2;
        float4 v = float4{0.f, 0.f, 0.f, 0.f};
        int row  = row0 + r;
        if (row < N) v = ((const float4*)(X + (size_t)row * HF))[idx4 & 15];
        *(float4*)&xs[r * 68 + kk] = v;
    }
    __syncthreads();

    const int rg = tid >> 4;
    const int cg = tid & 15;
    float4 a0 = float4{0.f, 0.f, 0.f, 0.f};
    float4 a1 = a0, a2 = a0, a3 = a0;

#pragma unroll
    for (int k = 0; k < 64; ++k) {
        float4 wv = *(float4*)&ws[k * 64 + cg * 4];
        float  x0 = xs[(rg * 4 + 0) * 68 + k];
        float  x1 = xs[(rg * 4 + 1) * 68 + k];
        float  x2 = xs[(rg * 4 + 2) * 68 + k];
        float  x3 = xs[(rg * 4 + 3) * 68 + k];
        a0.x += x0 * wv.x; a0.y += x0 * wv.y; a0.z += x0 * wv.z; a0.w += x0 * wv.w;
        a1.x += x1 * wv.x; a1.y += x1 * wv.y; a1.z += x1 * wv.z; a1.w += x1 * wv.w;
        a2.x += x2 * wv.x; a2.y += x2 * wv.y; a2.z += x2 * wv.z; a2.w += x2 * wv.w;
        a3.x += x3 * wv.x; a3.y += x3 * wv.y; a3.z += x3 * wv.z; a3.w += x3 * wv.w;
    }

    float4 accs[4] = {a0, a1, a2, a3};
#pragma unroll
    for (int j = 0; j < 4; ++j) {
        int row = row0 + rg * 4 + j;
        if (row < N) {
            float d = dis[row];
            float4 a = accs[j];
            ushort4 pk;
            pk.x = f2bf(d * a.x); pk.y = f2bf(d * a.y);
            pk.z = f2bf(d * a.z); pk.w = f2bf(d * a.w);
            *(ushort4*)&HS[(size_t)row * HF + cg * 4] = pk;
        }
    }
}

// ---- CSR gather (+ optional fused layer-2 transform) -----------------------
// row_n = relu( dis[n]*(sum_{r in nbrs(n)} hs[r] + hs[n]) + b )
// FUSE=1: out = bf16( dis[n] * (row_n @ W2) )   [= hs for next layer]
// FUSE=0: out = bf16( row_n )                   [= relu'd agg for pooling]
// One wave per node; 4 quarter-waves each gather a full 128B bf16 row.
template <int FUSE>
__global__ __launch_bounds__(256) void k_gather(const u32* __restrict__ rowptr,
                                                const int* __restrict__ eidx,
                                                const float* __restrict__ dis,
                                                const u32* __restrict__ hs,   // bf16 pairs
                                                const float* __restrict__ bvec,
                                                const float* __restrict__ W2,
                                                unsigned short* __restrict__ outbf,
                                                int N, int E) {
    __shared__ float w2s[64 * 64];
    __shared__ float rowLds[4 * 64];
    const int tid  = threadIdx.x;
    if (FUSE) {
        for (int i = tid; i < 64 * 64; i += 256) w2s[i] = W2[i];
    }
    const int wv   = tid >> 6;
    const int lane = tid & 63;
    const int q    = lane >> 4;      // quarter 0..3
    const int f4   = lane & 15;      // feature quad: feats 4*f4 .. 4*f4+3
    const int n    = blockIdx.x * 4 + wv;
    const bool act = (n < N);

    float4 acc = float4{0.f, 0.f, 0.f, 0.f};
    float dn = 0.f;
    if (act) {
        u32 start = rowptr[n];
        u32 end   = (n + 1 < N) ? rowptr[n + 1] : (u32)E;
        dn = dis[n];
        u32 e = start + q;
        for (; e + 4 < end; e += 8) {       // 2 edges per quarter per iter
            int r0 = eidx[e], r1 = eidx[e + 4];
            uint2 w0 = ((const uint2*)(hs + (size_t)r0 * 32))[f4];
            uint2 w1 = ((const uint2*)(hs + (size_t)r1 * 32))[f4];
            acc.x += bfl(w0.x) + bfl(w1.x);
            acc.y += bfh(w0.x) + bfh(w1.x);
            acc.z += bfl(w0.y) + bfl(w1.y);
            acc.w += bfh(w0.y) + bfh(w1.y);
        }
        if (e < end) {
            int r = eidx[e];
            uint2 w = ((const uint2*)(hs + (size_t)r * 32))[f4];
            acc.x += bfl(w.x); acc.y += bfh(w.x);
            acc.z += bfl(w.y); acc.w += bfh(w.y);
        }
        if (q == 0) {                        // self-loop
            uint2 w = ((const uint2*)(hs + (size_t)n * 32))[f4];
            acc.x += bfl(w.x); acc.y += bfh(w.x);
            acc.z += bfl(w.y); acc.w += bfh(w.y);
        }
    }
    // reduce across the 4 quarters (butterfly -> replicated in all lanes)
    acc.x += __shfl_xor(acc.x, 32); acc.y += __shfl_xor(acc.y, 32);
    acc.z += __shfl_xor(acc.z, 32); acc.w += __shfl_xor(acc.w, 32);
    acc.x += __shfl_xor(acc.x, 16); acc.y += __shfl_xor(acc.y, 16);
    acc.z += __shfl_xor(acc.z, 16); acc.w += __shfl_xor(acc.w, 16);

    float4 bv = ((const float4*)bvec)[f4];
    float4 g;
    g.x = fmaxf(dn * acc.x + bv.x, 0.f);
    g.y = fmaxf(dn * acc.y + bv.y, 0.f);
    g.z = fmaxf(dn * acc.z + bv.z, 0.f);
    g.w = fmaxf(dn * acc.w + bv.w, 0.f);

    if (FUSE) {
        if (act && q == 0) *(float4*)&rowLds[wv * 64 + f4 * 4] = g;
        __syncthreads();                     // also covers w2s staging
        if (act) {
            float a2 = 0.f;
#pragma unroll
            for (int k = 0; k < 64; ++k)
                a2 += rowLds[wv * 64 + k] * w2s[k * 64 + lane];
            outbf[(size_t)n * HF + lane] = f2bf(dn * a2);
        }
    } else {
        if (act && q == 0) {
            ushort4 pk;
            pk.x = f2bf(g.x); pk.y = f2bf(g.y);
            pk.z = f2bf(g.z); pk.w = f2bf(g.w);
            *(ushort4*)&outbf[(size_t)n * HF + f4 * 4] = pk;
        }
    }
}

// ---- pooling: one block per graph (batch sorted), bf16 in, no atomics ------
__device__ __forceinline__ int lower_bound(const int* __restrict__ a, int n, int key) {
    int lo = 0, hi = n;
    while (lo < hi) { int mid = (lo + hi) >> 1; if (a[mid] < key) lo = mid + 1; else hi = mid; }
    return lo;
}

__global__ __launch_bounds__(256) void k_pool(const u32* __restrict__ aggR,  // bf16 pairs
                                              const int* __restrict__ batch,
                                              float* __restrict__ gmean, int N) {
    __shared__ float red[4][64];
    const int g    = blockIdx.x;
    const int lane = threadIdx.x & 63;
    const int w    = threadIdx.x >> 6;
    int s = lower_bound(batch, N, g);
    int e = lower_bound(batch, N, g + 1);
    float acc = 0.f;
    for (int n = s + w; n < e; n += 4) {
        u32 wv = aggR[(size_t)n * 32 + (lane >> 1)];
        acc += (lane & 1) ? bfh(wv) : bfl(wv);
    }
    red[w][lane] = acc;
    __syncthreads();
    if (w == 0) {
        float t = red[0][lane] + red[1][lane] + red[2][lane] + red[3][lane];
        gmean[g * HF + lane] = t / fmaxf((float)(e - s), 1.0f);
    }
}

// ---- fused MLP head (one block; thread = graph) ----------------------------
__global__ __launch_bounds__(256) void k_head(const float* __restrict__ gmean,
                                              const float* __restrict__ Wl1,
                                              const float* __restrict__ bl1,
                                              const float* __restrict__ Wl2,
                                              const float* __restrict__ bl2,
                                              float* __restrict__ out) {
    __shared__ float w1[64 * 32];
    __shared__ float w2[64];
    __shared__ float bb1[32];
    const int tid = threadIdx.x;
    for (int i = tid; i < 64 * 32; i += 256) w1[i] = Wl1[i];
    if (tid < 64) w2[tid] = Wl2[tid];
    if (tid < 32) bb1[tid] = bl1[tid];
    __syncthreads();

    const int g = tid;  // 256 graphs
    float gm[64];
#pragma unroll
    for (int k = 0; k < 64; ++k) gm[k] = gmean[g * HF + k];
    float l0 = bl2[0], l1 = bl2[1];
#pragma unroll
    for (int j = 0; j < 32; ++j) {
        float a = bb1[j];
#pragma unroll
        for (int k = 0; k < 64; ++k) a += gm[k] * w1[k * 32 + j];
        a = fmaxf(a, 0.f);
        l0 += a * w2[2 * j];
        l1 += a * w2[2 * j + 1];
    }
    float m   = fmaxf(l0, l1);
    float lse = m + logf(expf(l0 - m) + expf(l1 - m));
    out[2 * g]     = l0 - lse;
    out[2 * g + 1] = l1 - lse;
}

// ---- driver ----------------------------------------------------------------
extern "C" void kernel_launch(void* const* d_in, const int* in_sizes, int n_in,
                              void* d_out, int out_size, void* d_ws, size_t ws_size,
                              hipStream_t stream) {
    const float* x   = (const float*)d_in[0];
    const int*   ei  = (const int*)d_in[1];
    const int*   bi  = (const int*)d_in[2];
    const float* W1  = (const float*)d_in[3];
    const float* b1  = (const float*)d_in[4];
    const float* W2  = (const float*)d_in[5];
    const float* b2  = (const float*)d_in[6];
    const float* Wl1 = (const float*)d_in[7];
    const float* bl1 = (const float*)d_in[8];
    const float* Wl2 = (const float*)d_in[9];
    const float* bl2 = (const float*)d_in[10];
    float* out = (float*)d_out;

    const int N = in_sizes[0] / HF;
    const int E = in_sizes[1] / 2;
    const int* rows = ei;
    const int* cols = ei + E;
    const int NB = (N + BSZ - 1) / BSZ;

    // workspace (4B units).
    // Aliases: part[] (E u32, dead after k_place2) shares hs2 (written later
    // by gather1); aggR (pool input) shares hs1 (dead after gather1).
    float* ws = (float*)d_ws;
    size_t o = 0;
    float* dis    = ws + o; o += ((size_t)N + 63) / 64 * 64;
    unsigned short* hs1 = (unsigned short*)(ws + o); o += (size_t)N * 32;  // bf16 N x 64
    unsigned short* hs2 = (unsigned short*)(ws + o); o += (size_t)N * 32;  // bf16 N x 64
    u32*   part   = (u32*)hs2;
    unsigned short* aggR = hs1;
    u32*   rowptr = (u32*)(ws + o); o += ((size_t)N + 63) / 64 * 64;
    int*   eidx   = (int*)(ws + o); o += (size_t)E;
    u32*   gbh    = (u32*)(ws + o); o += 256;
    u32*   bscan  = (u32*)(ws + o); o += 320;
    u32*   gcurb  = (u32*)(ws + o); o += 256;
    float* gmean  = ws + o; o += 256 * HF;

    const int gb = (N + 63) / 64;

    // CSR build (two-level bucket sort; shared by both layers)
    k_zero<<<1, 256, 0, stream>>>(gbh, 256);
    k_bhist<<<256, 256, 0, stream>>>(cols, gbh, E, NB);
    k_bscan<<<1, 256, 0, stream>>>(gbh, bscan, gcurb, NB, E);
    k_part<<<(E + PCHUNK - 1) / PCHUNK, 256, 0, stream>>>(rows, cols, gcurb, part, E);
    k_place2<<<NB, 256, 0, stream>>>(bscan, part, rowptr, dis, eidx, N);

    // layer 1 dense
    k_gemm1<<<gb, 256, 0, stream>>>(x, W1, dis, hs1, N);
    // layer-1 aggregate + fused layer-2 dense -> hs2
    k_gather<1><<<(N + 3) / 4, 256, 0, stream>>>(rowptr, eidx, dis, (const u32*)hs1,
                                                 b1, W2, hs2, N, E);
    // layer-2 aggregate -> relu'd agg (bf16)
    k_gather<0><<<(N + 3) / 4, 256, 0, stream>>>(rowptr, eidx, dis, (const u32*)hs2,
                                                 b2, nullptr, aggR, N, E);

    // mean pool + fused head
    k_pool<<<256, 256, 0, stream>>>((const u32*)aggR, bi, gmean, N);
    k_head<<<1, 256, 0, stream>>>(gmean, Wl1, bl1, Wl2, bl2, out);
}